// Round 16
// baseline (829.585 us; speedup 1.0000x reference)
//
#include <hip/hip_runtime.h>
#include <hip/hip_bf16.h>

typedef __attribute__((ext_vector_type(8))) __bf16 bf16x8;
typedef __attribute__((ext_vector_type(4))) float f32x4;
typedef __hip_bfloat16 bf16;

#define SCALE_Q 0.17677669529663687f

// global_load_lds: LDS dest linear (wave-uniform base + lane*16), source pre-swizzled per-lane.
#define LDSP(p) ((__attribute__((address_space(3))) unsigned int*)(unsigned long long)(p))
#define GPTR(p) ((const __attribute__((address_space(1))) unsigned int*)(unsigned long long)(p))
#define GLD16(gp, lp) __builtin_amdgcn_global_load_lds(GPTR(gp), LDSP(lp), 16, 0, 0)

// exact-grade GELU: Abramowitz-Stegun 7.1.26 erf (|err| < 1.5e-7)
__device__ inline float gelu_f(float x) {
  const float ax = fabsf(x) * 0.70710678118654752f;
  const float t = __builtin_amdgcn_rcpf(__builtin_fmaf(0.3275911f, ax, 1.0f));
  const float poly = t * __builtin_fmaf(t, __builtin_fmaf(t, __builtin_fmaf(t,
                     __builtin_fmaf(t, 1.061405429f, -1.453152027f),
                     1.421413741f), -0.284496736f), 0.254829592f);
  const float er = __builtin_fmaf(-poly, __expf(-ax * ax), 1.0f);
  return 0.5f * x * (1.0f + copysignf(er, x));
}

// ---------------- weight fp32 -> bf16 ----------------
__global__ void cvt_kernel(const float* __restrict__ in, bf16* __restrict__ out, int n) {
  int i = blockIdx.x * 256 + threadIdx.x;
  if (i < n) out[i] = __float2bfloat16(in[i]);
}

// ---- weight fp32 -> bf16 in MFMA B-fragment order ----
// src [N][K] row-major; dst chunk (n>>4, k>>5) holds [lg=(k>>3)&3][lr=n&15][e=k&7].
template<int K, int KC>
__global__ void cvt_frag_kernel(const float* __restrict__ in, bf16* __restrict__ out, int total) {
  int i = blockIdx.x * 256 + threadIdx.x;
  if (i < total) {
    const int n = i / K, k = i - n * K;
    out[((n >> 4) * KC + (k >> 5)) * 512 + ((k >> 3) & 3) * 128 + (n & 15) * 8 + (k & 7)] =
        __float2bfloat16(in[i]);
  }
}

// ---- LayerNorm1 fused with shifted-window gather, fp32 in -> bf16 out ----
__global__ __launch_bounds__(256) void ln_kernel(const float* __restrict__ in,
                                                 const float* __restrict__ gw,
                                                 const float* __restrict__ gb,
                                                 bf16* __restrict__ out) {
  const int t = blockIdx.x * 4 + (threadIdx.x >> 6);
  const int lane = threadIdx.x & 63;
  const int b_ = t >> 6, n = t & 63;
  const int b = b_ >> 10, wk = b_ & 1023, wi = wk >> 5, wj = wk & 31;
  const int i_ = n >> 3, j_ = n & 7;
  const int hf = (wi * 8 + i_ + 4) & 255, wf = (wj * 8 + j_ + 4) & 255;
  const long g = (((long)b * 256 + hf) * 256 + wf) * 192;
  const float x0 = in[g + lane], x1 = in[g + 64 + lane], x2 = in[g + 128 + lane];
  float s = x0 + x1 + x2;
  float s2 = x0 * x0 + x1 * x1 + x2 * x2;
  #pragma unroll
  for (int m = 1; m < 64; m <<= 1) { s += __shfl_xor(s, m); s2 += __shfl_xor(s2, m); }
  const float mu = s * (1.0f / 192.0f);
  const float rstd = rsqrtf(s2 * (1.0f / 192.0f) - mu * mu + 1e-5f);
  const long o = (long)t * 192;
  out[o + lane]       = __float2bfloat16((x0 - mu) * rstd * gw[lane]       + gb[lane]);
  out[o + 64 + lane]  = __float2bfloat16((x1 - mu) * rstd * gw[lane + 64]  + gb[lane + 64]);
  out[o + 128 + lane] = __float2bfloat16((x2 - mu) * rstd * gw[lane + 128] + gb[lane + 128]);
}

// ---------------- GEMM: C[m][n] = sum_k A[m][k] * W[n][k] (+bias), bf16 MFMA ----------------
// BM=128 BN=192 BK=64, 512 threads (8 waves, 4x2 grid, wave tile 32x96).
// EPI 0: qkv scatter (+q scale)   EPI 1: proj + window-reverse+roll + residual -> h_buf f32
template<int EPI>
__global__ __launch_bounds__(512, 4) void gemm_bt(const bf16* __restrict__ A,
                                                  const bf16* __restrict__ Bw,
                                                  const float* __restrict__ bias,
                                                  int K, void* __restrict__ outp,
                                                  const float* __restrict__ aux1,
                                                  const float* __restrict__ aux2) {
  __shared__ __align__(16) bf16 Ald[128 * 64];
  __shared__ __align__(16) bf16 Bld[192 * 64];
  const int tid = threadIdx.x;
  const int n0 = blockIdx.x * 192;
  const long m0 = (long)blockIdx.y * 128;
  const int lane = tid & 63, wid = tid >> 6;
  const int wr = (wid >> 1) * 32, wc = (wid & 1) * 96;
  const int lg = lane >> 4, lr = lane & 15;
  const int l3 = lane >> 3, l7 = lane & 7;
  const int chunk = l7 ^ l3;  // involutive source swizzle

  const bf16* aptr = A + (m0 + wid * 16 + l3) * (long)K + chunk * 8;
  const bf16* bptr = Bw + (n0 + wid * 24 + l3) * (long)K + chunk * 8;
  char* alds = (char*)Ald + wid * 16 * 128;
  char* blds = (char*)Bld + wid * 24 * 128;
  const long rk8 = 8 * (long)K;

  f32x4 acc[2][6];
  #pragma unroll
  for (int i = 0; i < 2; i++)
    #pragma unroll
    for (int j = 0; j < 6; j++) acc[i][j] = (f32x4){0.f, 0.f, 0.f, 0.f};

  for (int k0 = 0; k0 < K; k0 += 64) {
    GLD16(aptr + k0, alds);
    GLD16(aptr + rk8 + k0, alds + 1024);
    GLD16(bptr + k0, blds);
    GLD16(bptr + rk8 + k0, blds + 1024);
    GLD16(bptr + 2 * rk8 + k0, blds + 2048);
    __syncthreads();
    #pragma unroll
    for (int ks = 0; ks < 2; ks++) {
      bf16x8 af[2], bfr[6];
      #pragma unroll
      for (int i = 0; i < 2; i++) {
        const int row = wr + i * 16 + lr;
        af[i] = *(const bf16x8*)((const char*)Ald + row * 128 + (((ks * 4 + lg) ^ (row & 7)) * 16));
      }
      #pragma unroll
      for (int j = 0; j < 6; j++) {
        const int row = wc + j * 16 + lr;
        bfr[j] = *(const bf16x8*)((const char*)Bld + row * 128 + (((ks * 4 + lg) ^ (row & 7)) * 16));
      }
      #pragma unroll
      for (int i = 0; i < 2; i++)
        #pragma unroll
        for (int j = 0; j < 6; j++)
          acc[i][j] = __builtin_amdgcn_mfma_f32_16x16x32_bf16(af[i], bfr[j], acc[i][j], 0, 0, 0);
    }
    __syncthreads();
  }

  #pragma unroll
  for (int i = 0; i < 2; i++) {
    #pragma unroll
    for (int j = 0; j < 6; j++) {
      #pragma unroll
      for (int r = 0; r < 4; r++) {
        const long m = m0 + wr + i * 16 + lg * 4 + r;   // token row
        const int cn = n0 + wc + j * 16 + lr;           // output col
        float v = acc[i][j][r] + bias[cn];
        if (EPI == 0) {
          const long b_ = m >> 6; const int n = (int)(m & 63);
          const int which = cn / 192, rem = cn - which * 192, head = rem >> 5, d = rem & 31;
          if (which == 0) v *= SCALE_Q;
          ((bf16*)outp)[((b_ * 6 + head) * 3 + which) * 2048 + n * 32 + d] = __float2bfloat16(v);
        } else {
          const long b_ = m >> 6; const int n = (int)(m & 63);
          const int b = (int)(b_ >> 10), wk = (int)(b_ & 1023), wi = wk >> 5, wj = wk & 31;
          const int i_ = n >> 3, j_ = n & 7;
          const int hf = (wi * 8 + i_ + 4) & 255, wf = (wj * 8 + j_ + 4) & 255;
          const long g = (((long)b * 256 + hf) * 256 + wf) * 192 + cn;
          ((float*)outp)[g] = aux1[g] + v;   // h = shortcut + proj(attn)
        }
      }
    }
  }
}

// ------ fused MLP v7: out = h + fc2(gelu(fc1(LN2(h)))) — BM=64, half-G pipeline ------
// = v6 with the g tile split into column halves: fc1(cols h*384..+384) -> gelu -> G_half
// (48KB) -> fc2(k = h*384..+384), h = 0,1. LDS 120KB -> 72KB -> 2 blocks/CU (restores
// cross-block overlap that v6 lost) while keeping BM=64's halved weight traffic.
// fc2's global kt order is still 0..23 sequential; fc1 per-element kc order unchanged;
// gelu elementwise -> results bitwise-identical to v6.
__global__ __launch_bounds__(512, 4) void mlp_fused(const float* __restrict__ hbuf,
                                                    const float* __restrict__ n2w,
                                                    const float* __restrict__ n2b,
                                                    const bf16* __restrict__ w1t,
                                                    const float* __restrict__ b1,
                                                    const bf16* __restrict__ w2t,
                                                    const float* __restrict__ b2,
                                                    float* __restrict__ outp) {
  __shared__ __align__(16) char smem[73728];
  char* Ab = smem;          // h_ln tile: 3 groups x [64 rows][8 slots][16B] = 24576
  char* G  = smem + 24576;  // half-g tile: [64 rows][48 slots][16B] = 49152

  const int tid = threadIdx.x;
  const long m0 = (long)blockIdx.x * 64;
  const int lane = tid & 63, wid = tid >> 6;
  const int lg = lane >> 4, lr = lane & 15;

  // ---- LN2: each wave normalizes 8 rows of hbuf -> Ab (swizzled bf16; proven v6 code) ----
  #pragma unroll
  for (int t8 = 0; t8 < 8; t8++) {
    const int row = wid * 8 + t8;
    const long g = (m0 + row) * 192;
    const float x0 = hbuf[g + lane], x1 = hbuf[g + 64 + lane], x2 = hbuf[g + 128 + lane];
    float s = x0 + x1 + x2;
    float s2 = x0 * x0 + x1 * x1 + x2 * x2;
    #pragma unroll
    for (int msk = 1; msk < 64; msk <<= 1) { s += __shfl_xor(s, msk); s2 += __shfl_xor(s2, msk); }
    const float mu = s * (1.0f / 192.0f);
    const float rstd = rsqrtf(s2 * (1.0f / 192.0f) - mu * mu + 1e-5f);
    #pragma unroll
    for (int p = 0; p < 3; p++) {
      const int ch = p * 64 + lane;
      const float xv = (p == 0) ? x0 : (p == 1) ? x1 : x2;
      const float v = (xv - mu) * rstd * n2w[ch] + n2b[ch];
      const int c = (ch >> 3) & 7;               // chunk within 64-ch group
      const int slot = c ^ (row & 7);
      *(unsigned short*)(Ab + p * 8192 + row * 128 + slot * 16 + (ch & 7) * 2) =
          __builtin_bit_cast(unsigned short, __float2bfloat16(v));
    }
  }
  __syncthreads();

  const int wt = wid >> 2, wn = wid & 3;
  f32x4 acc2[2][3];
  #pragma unroll
  for (int i = 0; i < 2; i++)
    #pragma unroll
    for (int j = 0; j < 3; j++) acc2[i][j] = (f32x4){0.f, 0.f, 0.f, 0.f};

  #pragma unroll
  for (int h = 0; h < 2; h++) {
    // ---- fc1 half h: wave computes 48 cols (c16 chunks h*24 + wid*3 .. +3) ----
    f32x4 acc1[4][3];
    #pragma unroll
    for (int i = 0; i < 4; i++)
      #pragma unroll
      for (int j = 0; j < 3; j++) acc1[i][j] = (f32x4){0.f, 0.f, 0.f, 0.f};

    const int c16base = h * 24 + wid * 3;
    #pragma unroll
    for (int kc = 0; kc < 6; kc++) {
      const int q = kc >> 1;
      const int kk = (kc & 1) * 4 + lg;
      bf16x8 af[4], bfr[3];
      #pragma unroll
      for (int i = 0; i < 4; i++) {
        const int row = i * 16 + lr;
        af[i] = *(const bf16x8*)(Ab + q * 8192 + row * 128 + ((kk ^ (row & 7)) * 16));
      }
      #pragma unroll
      for (int j = 0; j < 3; j++)
        bfr[j] = *(const bf16x8*)(w1t + ((c16base + j) * 6 + kc) * 512 + lane * 8);
      #pragma unroll
      for (int i = 0; i < 4; i++)
        #pragma unroll
        for (int j = 0; j < 3; j++)
          acc1[i][j] = __builtin_amdgcn_mfma_f32_16x16x32_bf16(af[i], bfr[j], acc1[i][j], 0, 0, 0);
    }

    // barrier: (h=1) ensure fc2 half 0 finished reading G before overwrite
    __syncthreads();

    // gelu + write half-g tile to LDS (XOR-swizzled within the 48-slot half)
    #pragma unroll
    for (int j = 0; j < 3; j++) {
      const int nloc = wid * 48 + j * 16 + lr;        // col within half [0,384)
      const float bj = b1[h * 384 + nloc];
      const int c = nloc >> 3;                        // chunk 0..47
      #pragma unroll
      for (int i = 0; i < 4; i++) {
        #pragma unroll
        for (int r = 0; r < 4; r++) {
          const int m = i * 16 + lg * 4 + r;
          const int slot = (c & ~7) | ((c & 7) ^ (m & 7));
          *(unsigned short*)(G + m * 768 + slot * 16 + (nloc & 7) * 2) =
              __builtin_bit_cast(unsigned short, __float2bfloat16(gelu_f(acc1[i][j][r] + bj)));
        }
      }
    }
    __syncthreads();

    // ---- fc2 k-half h (A from G, w2t fragments from L2); global kt = h*12 + ktl ----
    for (int ktl = 0; ktl < 12; ktl++) {
      const int c2 = ktl * 4 + lg;  // local g chunk 0..47
      bf16x8 af2[2], bfr2[3];
      #pragma unroll
      for (int i = 0; i < 2; i++) {
        const int grow = wt * 32 + i * 16 + lr;
        const int slot2 = (c2 & ~7) | ((c2 & 7) ^ (grow & 7));
        af2[i] = *(const bf16x8*)(G + grow * 768 + slot2 * 16);
      }
      #pragma unroll
      for (int j = 0; j < 3; j++)
        bfr2[j] = *(const bf16x8*)(w2t + ((wn * 3 + j) * 24 + h * 12 + ktl) * 512 + lane * 8);
      #pragma unroll
      for (int i = 0; i < 2; i++)
        #pragma unroll
        for (int j = 0; j < 3; j++)
          acc2[i][j] = __builtin_amdgcn_mfma_f32_16x16x32_bf16(af2[i], bfr2[j], acc2[i][j], 0, 0, 0);
    }
  }

  // epilogue: + bias + residual h -> out (f32)
  #pragma unroll
  for (int j = 0; j < 3; j++) {
    const int cn = wn * 48 + j * 16 + lr;
    const float bj = b2[cn];
    #pragma unroll
    for (int i = 0; i < 2; i++) {
      #pragma unroll
      for (int r = 0; r < 4; r++) {
        const long m = m0 + wt * 32 + i * 16 + lg * 4 + r;
        outp[m * 192 + cn] = acc2[i][j][r] + bj + hbuf[m * 192 + cn];
      }
    }
  }
}

// ---------------- windowed attention: one wave per (window, head) — proven round-1 ----------------
__global__ __launch_bounds__(64) void attn_kernel(const bf16* __restrict__ qkv,
                                                  const float* __restrict__ rpb,
                                                  bf16* __restrict__ outp) {
  __shared__ __align__(16) char smem[14848];
  __shared__ float rps[225];
  const int bid = blockIdx.x;
  const int b_ = bid / 6, head = bid - b_ * 6;
  const int lane = threadIdx.x;
  const long base = ((long)b_ * 6 + head) * 3 * 2048;

  for (int t = lane; t < 225; t += 64) rps[t] = rpb[t * 6 + head];

  #pragma unroll
  for (int q = 0; q < 4; q++) {
    const int f = q * 64 + lane, row = f >> 2, c = f & 3;
    *(uint4*)(smem + row * 80 + c * 16) = *(const uint4*)(qkv + base + row * 32 + c * 8);
    *(uint4*)(smem + 5120 + row * 80 + c * 16) = *(const uint4*)(qkv + base + 2048 + row * 32 + c * 8);
  }
  {  // stage V transposed: Vt[d][m]
    const bf16* vsrc = qkv + base + 4096 + lane * 32;
    bf16 vv[32];
    #pragma unroll
    for (int q = 0; q < 4; q++) *(uint4*)&vv[q * 8] = *(const uint4*)(vsrc + q * 8);
    bf16* vt = (bf16*)(smem + 10240);
    #pragma unroll
    for (int d = 0; d < 32; d++) vt[d * 72 + lane] = vv[d];
  }
  __syncthreads();

  const int lg = lane >> 4, lr = lane & 15;
  const f32x4 z4 = {0.f, 0.f, 0.f, 0.f};
  f32x4 s[4][4];
  {
    bf16x8 a[4], b[4];
    #pragma unroll
    for (int fi = 0; fi < 4; fi++)
      a[fi] = *(const bf16x8*)(smem + (fi * 16 + lr) * 80 + lg * 16);
    #pragma unroll
    for (int fj = 0; fj < 4; fj++)
      b[fj] = *(const bf16x8*)(smem + 5120 + (fj * 16 + lr) * 80 + lg * 16);
    #pragma unroll
    for (int fi = 0; fi < 4; fi++)
      #pragma unroll
      for (int fj = 0; fj < 4; fj++)
        s[fi][fj] = __builtin_amdgcn_mfma_f32_16x16x32_bf16(a[fi], b[fj], z4, 0, 0, 0);
  }

  const int wk = b_ & 1023; const int wi = wk >> 5, wj = wk & 31;
  const bool eh = (wi == 31), ew = (wj == 31);
  bf16* P = (bf16*)smem;
  #pragma unroll
  for (int fi = 0; fi < 4; fi++) {
    #pragma unroll
    for (int r = 0; r < 4; r++) {
      const int n = fi * 16 + lg * 4 + r;
      const int i1 = n >> 3, j1 = n & 7;
      const int labn = (eh ? (i1 < 4 ? 3 : 6) : 0) + (ew ? (j1 < 4 ? 1 : 2) : 0);
      float vals[4];
      #pragma unroll
      for (int fj = 0; fj < 4; fj++) {
        const int m = fj * 16 + lr;
        const int i2 = m >> 3, j2 = m & 7;
        const int labm = (eh ? (i2 < 4 ? 3 : 6) : 0) + (ew ? (j2 < 4 ? 1 : 2) : 0);
        vals[fj] = s[fi][fj][r] + rps[(i1 - i2 + 7) * 15 + (j1 - j2 + 7)]
                 + (labn != labm ? -100.0f : 0.0f);
      }
      float mx = fmaxf(fmaxf(vals[0], vals[1]), fmaxf(vals[2], vals[3]));
      #pragma unroll
      for (int msk = 1; msk < 16; msk <<= 1) mx = fmaxf(mx, __shfl_xor(mx, msk));
      float pe[4]; float sum = 0.f;
      #pragma unroll
      for (int fj = 0; fj < 4; fj++) { pe[fj] = __expf(vals[fj] - mx); sum += pe[fj]; }
      #pragma unroll
      for (int msk = 1; msk < 16; msk <<= 1) sum += __shfl_xor(sum, msk);
      const float rinv = 1.0f / sum;
      #pragma unroll
      for (int fj = 0; fj < 4; fj++)
        P[n * 72 + fj * 16 + lr] = __float2bfloat16(pe[fj] * rinv);
    }
  }
  __syncthreads();

  f32x4 o[4][2];
  #pragma unroll
  for (int fi = 0; fi < 4; fi++)
    #pragma unroll
    for (int fd = 0; fd < 2; fd++) o[fi][fd] = z4;
  const bf16* vt = (const bf16*)(smem + 10240);
  #pragma unroll
  for (int ks = 0; ks < 2; ks++) {
    bf16x8 pa[4], vb[2];
    #pragma unroll
    for (int fi = 0; fi < 4; fi++)
      pa[fi] = *(const bf16x8*)(P + (fi * 16 + lr) * 72 + ks * 32 + lg * 8);
    #pragma unroll
    for (int fd = 0; fd < 2; fd++)
      vb[fd] = *(const bf16x8*)(vt + (fd * 16 + lr) * 72 + ks * 32 + lg * 8);
    #pragma unroll
    for (int fi = 0; fi < 4; fi++)
      #pragma unroll
      for (int fd = 0; fd < 2; fd++)
        o[fi][fd] = __builtin_amdgcn_mfma_f32_16x16x32_bf16(pa[fi], vb[fd], o[fi][fd], 0, 0, 0);
  }
  #pragma unroll
  for (int fi = 0; fi < 4; fi++)
    #pragma unroll
    for (int fd = 0; fd < 2; fd++)
      #pragma unroll
      for (int r = 0; r < 4; r++) {
        const int n = fi * 16 + lg * 4 + r;
        outp[((long)b_ * 64 + n) * 192 + head * 32 + fd * 16 + lr] = __float2bfloat16(o[fi][fd][r]);
      }
}

extern "C" void kernel_launch(void* const* d_in, const int* in_sizes, int n_in,
                              void* d_out, int out_size, void* d_ws, size_t ws_size,
                              hipStream_t stream) {
  const float* x      = (const float*)d_in[0];
  const float* qkv_w  = (const float*)d_in[1];
  const float* qkv_b  = (const float*)d_in[2];
  const float* proj_w = (const float*)d_in[3];
  const float* proj_b = (const float*)d_in[4];
  const float* rpb    = (const float*)d_in[5];
  const float* n1_w   = (const float*)d_in[6];
  const float* n1_b   = (const float*)d_in[7];
  const float* n2_w   = (const float*)d_in[8];
  const float* n2_b   = (const float*)d_in[9];
  const float* fc1_w  = (const float*)d_in[10];
  const float* fc1_b  = (const float*)d_in[11];
  const float* fc2_w  = (const float*)d_in[12];
  const float* fc2_b  = (const float*)d_in[13];

  char* ws = (char*)d_ws;
  // workspace layout — round-1/5 proven layout (g + hln regions unused):
  // [0, 884736)             weights bf16 (fc1/fc2 in fragment order)
  // [1 MiB, +100663296)     R1: zw -> attn_out  (bf16, M x 192)
  // [101711872, +402653184) R2: qkv (M x 576)  (bf16)
  // [504365056, +201326592) R3: h_buf (M x 192 f32, original token order)
  bf16* qkvw_h  = (bf16*)(ws);
  bf16* projw_h = (bf16*)(ws + 221184);
  bf16* fc1w_t  = (bf16*)(ws + 294912);
  bf16* fc2w_t  = (bf16*)(ws + 589824);
  bf16* r1      = (bf16*)(ws + (1L << 20));
  bf16* r2      = (bf16*)(ws + 101711872L);
  float* hbuf   = (float*)(ws + 504365056L);

  cvt_kernel<<<432, 256, 0, stream>>>(qkv_w, qkvw_h, 110592);
  cvt_kernel<<<144, 256, 0, stream>>>(proj_w, projw_h, 36864);
  cvt_frag_kernel<192, 6><<<576, 256, 0, stream>>>(fc1_w, fc1w_t, 147456);
  cvt_frag_kernel<768, 24><<<576, 256, 0, stream>>>(fc2_w, fc2w_t, 147456);

  // LN1 + roll + window partition -> zw (r1)
  ln_kernel<<<65536, 256, 0, stream>>>(x, n1_w, n1_b, r1);
  // QKV: zw @ qkv_w^T -> per-(window,head) Q|K|V blocks (r2)
  gemm_bt<0><<<dim3(3, 2048), 512, 0, stream>>>(r1, qkvw_h, qkv_b, 192, r2, nullptr, nullptr);
  // windowed attention -> attn_out (r1)
  attn_kernel<<<24576, 64, 0, stream>>>(r2, rpb, r1);
  // proj + window-reverse + roll + residual -> h_buf (r3, original order)
  gemm_bt<1><<<dim3(1, 2048), 512, 0, stream>>>(r1, projw_h, proj_b, 192, hbuf, x, nullptr);
  // fused LN2 + MLP: out = h + fc2(gelu(fc1(LN2(h))))
  mlp_fused<<<4096, 512, 0, stream>>>(hbuf, n2_w, n2_b, fc1w_t, fc1_b, fc2w_t, fc2_b,
                                      (float*)d_out);
}

// Round 17
// 828.790 us; speedup vs baseline: 1.0010x; 1.0010x over previous
//
#include <hip/hip_runtime.h>
#include <hip/hip_bf16.h>

typedef __attribute__((ext_vector_type(8))) __bf16 bf16x8;
typedef __attribute__((ext_vector_type(4))) float f32x4;
typedef __hip_bfloat16 bf16;

#define SCALE_Q 0.17677669529663687f

// global_load_lds: LDS dest linear (wave-uniform base + lane*16), source pre-swizzled per-lane.
#define LDSP(p) ((__attribute__((address_space(3))) unsigned int*)(unsigned long long)(p))
#define GPTR(p) ((const __attribute__((address_space(1))) unsigned int*)(unsigned long long)(p))
#define GLD16(gp, lp) __builtin_amdgcn_global_load_lds(GPTR(gp), LDSP(lp), 16, 0, 0)

// exact-grade GELU: Abramowitz-Stegun 7.1.26 erf (|err| < 1.5e-7)
__device__ inline float gelu_f(float x) {
  const float ax = fabsf(x) * 0.70710678118654752f;
  const float t = __builtin_amdgcn_rcpf(__builtin_fmaf(0.3275911f, ax, 1.0f));
  const float poly = t * __builtin_fmaf(t, __builtin_fmaf(t, __builtin_fmaf(t,
                     __builtin_fmaf(t, 1.061405429f, -1.453152027f),
                     1.421413741f), -0.284496736f), 0.254829592f);
  const float er = __builtin_fmaf(-poly, __expf(-ax * ax), 1.0f);
  return 0.5f * x * (1.0f + copysignf(er, x));
}

// ---- weight fp32 -> bf16 in MFMA B-fragment order ----
// src [N][K] row-major; dst chunk (n>>4, k>>5) holds [lg=(k>>3)&3][lr=n&15][e=k&7].
// Wave load for (c16,kc): base + (c16*KC+kc)*512 + lane*8 -> 1KB fully coalesced.
template<int K, int KC>
__global__ void cvt_frag_kernel(const float* __restrict__ in, bf16* __restrict__ out, int total) {
  int i = blockIdx.x * 256 + threadIdx.x;
  if (i < total) {
    const int n = i / K, k = i - n * K;
    out[((n >> 4) * KC + (k >> 5)) * 512 + ((k >> 3) & 3) * 128 + (n & 15) * 8 + (k & 7)] =
        __float2bfloat16(in[i]);
  }
}

// ---- LayerNorm1 fused with shifted-window gather, fp32 in -> bf16 out ----
__global__ __launch_bounds__(256) void ln_kernel(const float* __restrict__ in,
                                                 const float* __restrict__ gw,
                                                 const float* __restrict__ gb,
                                                 bf16* __restrict__ out) {
  const int t = blockIdx.x * 4 + (threadIdx.x >> 6);
  const int lane = threadIdx.x & 63;
  const int b_ = t >> 6, n = t & 63;
  const int b = b_ >> 10, wk = b_ & 1023, wi = wk >> 5, wj = wk & 31;
  const int i_ = n >> 3, j_ = n & 7;
  const int hf = (wi * 8 + i_ + 4) & 255, wf = (wj * 8 + j_ + 4) & 255;
  const long g = (((long)b * 256 + hf) * 256 + wf) * 192;
  const float x0 = in[g + lane], x1 = in[g + 64 + lane], x2 = in[g + 128 + lane];
  float s = x0 + x1 + x2;
  float s2 = x0 * x0 + x1 * x1 + x2 * x2;
  #pragma unroll
  for (int m = 1; m < 64; m <<= 1) { s += __shfl_xor(s, m); s2 += __shfl_xor(s2, m); }
  const float mu = s * (1.0f / 192.0f);
  const float rstd = rsqrtf(s2 * (1.0f / 192.0f) - mu * mu + 1e-5f);
  const long o = (long)t * 192;
  out[o + lane]       = __float2bfloat16((x0 - mu) * rstd * gw[lane]       + gb[lane]);
  out[o + 64 + lane]  = __float2bfloat16((x1 - mu) * rstd * gw[lane + 64]  + gb[lane + 64]);
  out[o + 128 + lane] = __float2bfloat16((x2 - mu) * rstd * gw[lane + 128] + gb[lane + 128]);
}

// ------- GEMM (K=192), "fc1 pattern": A staged ONCE in LDS, B fragments direct from L2 -------
// BM=128, 512 threads (8 waves as 4 row-groups x 2 col-groups of 96). 1 barrier total.
// A-tile: 3 groups x [128 rows][8 slots][16B] = 48KB, slot s of row r = chunk s^(r&7)
// (same proven swizzle as gemm_bt). B: fragment-order weights, 1KB coalesced per load.
// kc=0..5 ascending == old (k0,ks) order -> bitwise-identical accumulation.
// EPI 0: qkv scatter (+q scale)   EPI 1: proj + window-reverse+roll + residual -> h_buf f32
template<int EPI>
__global__ __launch_bounds__(512, 4) void gemm_fragB(const bf16* __restrict__ A,
                                                     const bf16* __restrict__ Bwt,
                                                     const float* __restrict__ bias,
                                                     void* __restrict__ outp,
                                                     const float* __restrict__ aux1) {
  __shared__ __align__(16) char Ab[49152];
  const int tid = threadIdx.x;
  const int n0 = blockIdx.x * 192;
  const long m0 = (long)blockIdx.y * 128;
  const int lane = tid & 63, wid = tid >> 6;
  const int wr = (wid >> 1) * 32, wc = (wid & 1) * 96;
  const int lg = lane >> 4, lr = lane & 15;
  const int l3 = lane >> 3, l7 = lane & 7;
  const int chunk = l7 ^ l3;  // involutive source swizzle

  // stage A once: per wave rows wid*16..+16, 3 k-groups, 6 GLD16
  {
    const bf16* aptr = A + (m0 + wid * 16 + l3) * 192 + chunk * 8;
    char* alds = Ab + wid * 2048;
    #pragma unroll
    for (int q = 0; q < 3; q++) {
      GLD16(aptr + q * 64, alds + q * 16384);
      GLD16(aptr + 8 * 192 + q * 64, alds + q * 16384 + 1024);
    }
  }
  __syncthreads();

  f32x4 acc[2][6];
  #pragma unroll
  for (int i = 0; i < 2; i++)
    #pragma unroll
    for (int j = 0; j < 6; j++) acc[i][j] = (f32x4){0.f, 0.f, 0.f, 0.f};

  const int c16base = (n0 >> 4) + (wid & 1) * 6;
  #pragma unroll
  for (int kc = 0; kc < 6; kc++) {
    const int q = kc >> 1;
    const int kk = (kc & 1) * 4 + lg;
    bf16x8 af[2], bfr[6];
    #pragma unroll
    for (int i = 0; i < 2; i++) {
      const int row = wr + i * 16 + lr;
      af[i] = *(const bf16x8*)(Ab + q * 16384 + row * 128 + ((kk ^ (row & 7)) * 16));
    }
    #pragma unroll
    for (int j = 0; j < 6; j++)
      bfr[j] = *(const bf16x8*)(Bwt + ((c16base + j) * 6 + kc) * 512 + lane * 8);
    #pragma unroll
    for (int i = 0; i < 2; i++)
      #pragma unroll
      for (int j = 0; j < 6; j++)
        acc[i][j] = __builtin_amdgcn_mfma_f32_16x16x32_bf16(af[i], bfr[j], acc[i][j], 0, 0, 0);
  }

  #pragma unroll
  for (int i = 0; i < 2; i++) {
    #pragma unroll
    for (int j = 0; j < 6; j++) {
      #pragma unroll
      for (int r = 0; r < 4; r++) {
        const long m = m0 + wr + i * 16 + lg * 4 + r;   // token row
        const int cn = n0 + wc + j * 16 + lr;           // output col
        float v = acc[i][j][r] + bias[cn];
        if (EPI == 0) {
          const long b_ = m >> 6; const int n = (int)(m & 63);
          const int which = cn / 192, rem = cn - which * 192, head = rem >> 5, d = rem & 31;
          if (which == 0) v *= SCALE_Q;
          ((bf16*)outp)[((b_ * 6 + head) * 3 + which) * 2048 + n * 32 + d] = __float2bfloat16(v);
        } else {
          const long b_ = m >> 6; const int n = (int)(m & 63);
          const int b = (int)(b_ >> 10), wk = (int)(b_ & 1023), wi = wk >> 5, wj = wk & 31;
          const int i_ = n >> 3, j_ = n & 7;
          const int hf = (wi * 8 + i_ + 4) & 255, wf = (wj * 8 + j_ + 4) & 255;
          const long g = (((long)b * 256 + hf) * 256 + wf) * 192 + cn;
          ((float*)outp)[g] = aux1[g] + v;   // h = shortcut + proj(attn)
        }
      }
    }
  }
}

// ------------ fused MLP v6 (best: 409us): out = h + fc2(gelu(fc1(LN2(h)))) — BM=64 ------------
__global__ __launch_bounds__(512, 2) void mlp_fused(const float* __restrict__ hbuf,
                                                    const float* __restrict__ n2w,
                                                    const float* __restrict__ n2b,
                                                    const bf16* __restrict__ w1t,
                                                    const float* __restrict__ b1,
                                                    const bf16* __restrict__ w2t,
                                                    const float* __restrict__ b2,
                                                    float* __restrict__ outp) {
  __shared__ __align__(16) char smem[122880];
  char* Ab = smem;          // h_ln tile: 3 groups x [64 rows][8 slots][16B] = 24576
  char* G  = smem + 24576;  // g tile: [64 rows][96 slots][16B] = 98304

  const int tid = threadIdx.x;
  const long m0 = (long)blockIdx.x * 64;
  const int lane = tid & 63, wid = tid >> 6;
  const int lg = lane >> 4, lr = lane & 15;

  // ---- LN2: each wave normalizes 8 rows of hbuf -> Ab (swizzled bf16) ----
  #pragma unroll
  for (int t8 = 0; t8 < 8; t8++) {
    const int row = wid * 8 + t8;
    const long g = (m0 + row) * 192;
    const float x0 = hbuf[g + lane], x1 = hbuf[g + 64 + lane], x2 = hbuf[g + 128 + lane];
    float s = x0 + x1 + x2;
    float s2 = x0 * x0 + x1 * x1 + x2 * x2;
    #pragma unroll
    for (int msk = 1; msk < 64; msk <<= 1) { s += __shfl_xor(s, msk); s2 += __shfl_xor(s2, msk); }
    const float mu = s * (1.0f / 192.0f);
    const float rstd = rsqrtf(s2 * (1.0f / 192.0f) - mu * mu + 1e-5f);
    #pragma unroll
    for (int p = 0; p < 3; p++) {
      const int ch = p * 64 + lane;
      const float xv = (p == 0) ? x0 : (p == 1) ? x1 : x2;
      const float v = (xv - mu) * rstd * n2w[ch] + n2b[ch];
      const int c = (ch >> 3) & 7;               // chunk within 64-ch group
      const int slot = c ^ (row & 7);
      *(unsigned short*)(Ab + p * 8192 + row * 128 + slot * 16 + (ch & 7) * 2) =
          __builtin_bit_cast(unsigned short, __float2bfloat16(v));
    }
  }
  __syncthreads();

  // ---------------- fc1: barrier-free k-loop (A from LDS, w1t fragments from L2) ----------------
  f32x4 acc1[4][6];
  #pragma unroll
  for (int i = 0; i < 4; i++)
    #pragma unroll
    for (int j = 0; j < 6; j++) acc1[i][j] = (f32x4){0.f, 0.f, 0.f, 0.f};

  const int c16base = wid * 6;  // wave cols = wid*96 .. +96
  #pragma unroll
  for (int kc = 0; kc < 6; kc++) {
    const int q = kc >> 1;
    const int kk = (kc & 1) * 4 + lg;
    bf16x8 af[4], bfr[6];
    #pragma unroll
    for (int i = 0; i < 4; i++) {
      const int row = i * 16 + lr;
      af[i] = *(const bf16x8*)(Ab + q * 8192 + row * 128 + ((kk ^ (row & 7)) * 16));
    }
    #pragma unroll
    for (int j = 0; j < 6; j++)
      bfr[j] = *(const bf16x8*)(w1t + ((c16base + j) * 6 + kc) * 512 + lane * 8);
    #pragma unroll
    for (int i = 0; i < 4; i++)
      #pragma unroll
      for (int j = 0; j < 6; j++)
        acc1[i][j] = __builtin_amdgcn_mfma_f32_16x16x32_bf16(af[i], bfr[j], acc1[i][j], 0, 0, 0);
  }

  // gelu + write g tile to LDS (XOR-swizzled; proven v2/v3 code)
  #pragma unroll
  for (int j = 0; j < 6; j++) {
    const int n = wid * 96 + j * 16 + lr;
    const float bj = b1[n];
    const int c = n >> 3;
    #pragma unroll
    for (int i = 0; i < 4; i++) {
      #pragma unroll
      for (int r = 0; r < 4; r++) {
        const int m = i * 16 + lg * 4 + r;
        const int slot = (c & ~7) | ((c & 7) ^ (m & 7));
        *(unsigned short*)(G + m * 1536 + slot * 16 + (n & 7) * 2) =
            __builtin_bit_cast(unsigned short, __float2bfloat16(gelu_f(acc1[i][j][r] + bj)));
      }
    }
  }
  __syncthreads();

  // ---------------- fc2: runtime k-loop (A from LDS g, w2t fragments from L2) ----------------
  const int wt = wid >> 2, wn = wid & 3;
  f32x4 acc2[2][3];
  #pragma unroll
  for (int i = 0; i < 2; i++)
    #pragma unroll
    for (int j = 0; j < 3; j++) acc2[i][j] = (f32x4){0.f, 0.f, 0.f, 0.f};

  for (int kt = 0; kt < 24; kt++) {
    const int c2 = kt * 4 + lg;  // global g chunk 0..95
    bf16x8 af2[2], bfr2[3];
    #pragma unroll
    for (int i = 0; i < 2; i++) {
      const int grow = wt * 32 + i * 16 + lr;
      const int slot2 = (c2 & ~7) | ((c2 & 7) ^ (grow & 7));
      af2[i] = *(const bf16x8*)(G + grow * 1536 + slot2 * 16);
    }
    #pragma unroll
    for (int j = 0; j < 3; j++)
      bfr2[j] = *(const bf16x8*)(w2t + ((wn * 3 + j) * 24 + kt) * 512 + lane * 8);
    #pragma unroll
    for (int i = 0; i < 2; i++)
      #pragma unroll
      for (int j = 0; j < 3; j++)
        acc2[i][j] = __builtin_amdgcn_mfma_f32_16x16x32_bf16(af2[i], bfr2[j], acc2[i][j], 0, 0, 0);
  }

  // epilogue: + bias + residual h -> out (f32)
  #pragma unroll
  for (int j = 0; j < 3; j++) {
    const int cn = wn * 48 + j * 16 + lr;
    const float bj = b2[cn];
    #pragma unroll
    for (int i = 0; i < 2; i++) {
      #pragma unroll
      for (int r = 0; r < 4; r++) {
        const long m = m0 + wt * 32 + i * 16 + lg * 4 + r;
        outp[m * 192 + cn] = acc2[i][j][r] + bj + hbuf[m * 192 + cn];
      }
    }
  }
}

// ---------------- windowed attention: one wave per (window, head) — proven round-1 ----------------
__global__ __launch_bounds__(64) void attn_kernel(const bf16* __restrict__ qkv,
                                                  const float* __restrict__ rpb,
                                                  bf16* __restrict__ outp) {
  __shared__ __align__(16) char smem[14848];
  __shared__ float rps[225];
  const int bid = blockIdx.x;
  const int b_ = bid / 6, head = bid - b_ * 6;
  const int lane = threadIdx.x;
  const long base = ((long)b_ * 6 + head) * 3 * 2048;

  for (int t = lane; t < 225; t += 64) rps[t] = rpb[t * 6 + head];

  #pragma unroll
  for (int q = 0; q < 4; q++) {
    const int f = q * 64 + lane, row = f >> 2, c = f & 3;
    *(uint4*)(smem + row * 80 + c * 16) = *(const uint4*)(qkv + base + row * 32 + c * 8);
    *(uint4*)(smem + 5120 + row * 80 + c * 16) = *(const uint4*)(qkv + base + 2048 + row * 32 + c * 8);
  }
  {  // stage V transposed: Vt[d][m]
    const bf16* vsrc = qkv + base + 4096 + lane * 32;
    bf16 vv[32];
    #pragma unroll
    for (int q = 0; q < 4; q++) *(uint4*)&vv[q * 8] = *(const uint4*)(vsrc + q * 8);
    bf16* vt = (bf16*)(smem + 10240);
    #pragma unroll
    for (int d = 0; d < 32; d++) vt[d * 72 + lane] = vv[d];
  }
  __syncthreads();

  const int lg = lane >> 4, lr = lane & 15;
  const f32x4 z4 = {0.f, 0.f, 0.f, 0.f};
  f32x4 s[4][4];
  {
    bf16x8 a[4], b[4];
    #pragma unroll
    for (int fi = 0; fi < 4; fi++)
      a[fi] = *(const bf16x8*)(smem + (fi * 16 + lr) * 80 + lg * 16);
    #pragma unroll
    for (int fj = 0; fj < 4; fj++)
      b[fj] = *(const bf16x8*)(smem + 5120 + (fj * 16 + lr) * 80 + lg * 16);
    #pragma unroll
    for (int fi = 0; fi < 4; fi++)
      #pragma unroll
      for (int fj = 0; fj < 4; fj++)
        s[fi][fj] = __builtin_amdgcn_mfma_f32_16x16x32_bf16(a[fi], b[fj], z4, 0, 0, 0);
  }

  const int wk = b_ & 1023; const int wi = wk >> 5, wj = wk & 31;
  const bool eh = (wi == 31), ew = (wj == 31);
  bf16* P = (bf16*)smem;
  #pragma unroll
  for (int fi = 0; fi < 4; fi++) {
    #pragma unroll
    for (int r = 0; r < 4; r++) {
      const int n = fi * 16 + lg * 4 + r;
      const int i1 = n >> 3, j1 = n & 7;
      const int labn = (eh ? (i1 < 4 ? 3 : 6) : 0) + (ew ? (j1 < 4 ? 1 : 2) : 0);
      float vals[4];
      #pragma unroll
      for (int fj = 0; fj < 4; fj++) {
        const int m = fj * 16 + lr;
        const int i2 = m >> 3, j2 = m & 7;
        const int labm = (eh ? (i2 < 4 ? 3 : 6) : 0) + (ew ? (j2 < 4 ? 1 : 2) : 0);
        vals[fj] = s[fi][fj][r] + rps[(i1 - i2 + 7) * 15 + (j1 - j2 + 7)]
                 + (labn != labm ? -100.0f : 0.0f);
      }
      float mx = fmaxf(fmaxf(vals[0], vals[1]), fmaxf(vals[2], vals[3]));
      #pragma unroll
      for (int msk = 1; msk < 16; msk <<= 1) mx = fmaxf(mx, __shfl_xor(mx, msk));
      float pe[4]; float sum = 0.f;
      #pragma unroll
      for (int fj = 0; fj < 4; fj++) { pe[fj] = __expf(vals[fj] - mx); sum += pe[fj]; }
      #pragma unroll
      for (int msk = 1; msk < 16; msk <<= 1) sum += __shfl_xor(sum, msk);
      const float rinv = 1.0f / sum;
      #pragma unroll
      for (int fj = 0; fj < 4; fj++)
        P[n * 72 + fj * 16 + lr] = __float2bfloat16(pe[fj] * rinv);
    }
  }
  __syncthreads();

  f32x4 o[4][2];
  #pragma unroll
  for (int fi = 0; fi < 4; fi++)
    #pragma unroll
    for (int fd = 0; fd < 2; fd++) o[fi][fd] = z4;
  const bf16* vt = (const bf16*)(smem + 10240);
  #pragma unroll
  for (int ks = 0; ks < 2; ks++) {
    bf16x8 pa[4], vb[2];
    #pragma unroll
    for (int fi = 0; fi < 4; fi++)
      pa[fi] = *(const bf16x8*)(P + (fi * 16 + lr) * 72 + ks * 32 + lg * 8);
    #pragma unroll
    for (int fd = 0; fd < 2; fd++)
      vb[fd] = *(const bf16x8*)(vt + (fd * 16 + lr) * 72 + ks * 32 + lg * 8);
    #pragma unroll
    for (int fi = 0; fi < 4; fi++)
      #pragma unroll
      for (int fd = 0; fd < 2; fd++)
        o[fi][fd] = __builtin_amdgcn_mfma_f32_16x16x32_bf16(pa[fi], vb[fd], o[fi][fd], 0, 0, 0);
  }
  #pragma unroll
  for (int fi = 0; fi < 4; fi++)
    #pragma unroll
    for (int fd = 0; fd < 2; fd++)
      #pragma unroll
      for (int r = 0; r < 4; r++) {
        const int n = fi * 16 + lg * 4 + r;
        outp[((long)b_ * 64 + n) * 192 + head * 32 + fd * 16 + lr] = __float2bfloat16(o[fi][fd][r]);
      }
}

extern "C" void kernel_launch(void* const* d_in, const int* in_sizes, int n_in,
                              void* d_out, int out_size, void* d_ws, size_t ws_size,
                              hipStream_t stream) {
  const float* x      = (const float*)d_in[0];
  const float* qkv_w  = (const float*)d_in[1];
  const float* qkv_b  = (const float*)d_in[2];
  const float* proj_w = (const float*)d_in[3];
  const float* proj_b = (const float*)d_in[4];
  const float* rpb    = (const float*)d_in[5];
  const float* n1_w   = (const float*)d_in[6];
  const float* n1_b   = (const float*)d_in[7];
  const float* n2_w   = (const float*)d_in[8];
  const float* n2_b   = (const float*)d_in[9];
  const float* fc1_w  = (const float*)d_in[10];
  const float* fc1_b  = (const float*)d_in[11];
  const float* fc2_w  = (const float*)d_in[12];
  const float* fc2_b  = (const float*)d_in[13];

  char* ws = (char*)d_ws;
  // workspace layout — proven layout; ALL weights now in fragment order:
  // [0, 221184)             qkv_w frags | [221184, 294912) proj_w frags
  // [294912, 589824)        fc1_w frags | [589824, 884736) fc2_w frags
  // [1 MiB, +100663296)     R1: zw -> attn_out  (bf16, M x 192)
  // [101711872, +402653184) R2: qkv (M x 576)  (bf16)
  // [504365056, +201326592) R3: h_buf (M x 192 f32, original token order)
  bf16* qkvw_t  = (bf16*)(ws);
  bf16* projw_t = (bf16*)(ws + 221184);
  bf16* fc1w_t  = (bf16*)(ws + 294912);
  bf16* fc2w_t  = (bf16*)(ws + 589824);
  bf16* r1      = (bf16*)(ws + (1L << 20));
  bf16* r2      = (bf16*)(ws + 101711872L);
  float* hbuf   = (float*)(ws + 504365056L);

  cvt_frag_kernel<192, 6><<<432, 256, 0, stream>>>(qkv_w, qkvw_t, 110592);
  cvt_frag_kernel<192, 6><<<144, 256, 0, stream>>>(proj_w, projw_t, 36864);
  cvt_frag_kernel<192, 6><<<576, 256, 0, stream>>>(fc1_w, fc1w_t, 147456);
  cvt_frag_kernel<768, 24><<<576, 256, 0, stream>>>(fc2_w, fc2w_t, 147456);

  // LN1 + roll + window partition -> zw (r1)
  ln_kernel<<<65536, 256, 0, stream>>>(x, n1_w, n1_b, r1);
  // QKV: zw @ qkv_w^T -> per-(window,head) Q|K|V blocks (r2)
  gemm_fragB<0><<<dim3(3, 2048), 512, 0, stream>>>(r1, qkvw_t, qkv_b, r2, nullptr);
  // windowed attention -> attn_out (r1)
  attn_kernel<<<24576, 64, 0, stream>>>(r2, rpb, r1);
  // proj + window-reverse + roll + residual -> h_buf (r3, original order)
  gemm_fragB<1><<<dim3(1, 2048), 512, 0, stream>>>(r1, projw_t, proj_b, hbuf, x);
  // fused LN2 + MLP: out = h + fc2(gelu(fc1(LN2(h))))
  mlp_fused<<<4096, 512, 0, stream>>>(hbuf, n2_w, n2_b, fc1w_t, fc1_b, fc2w_t, fc2_b,
                                      (float*)d_out);
}

// Round 18
// 803.750 us; speedup vs baseline: 1.0321x; 1.0312x over previous
//
#include <hip/hip_runtime.h>
#include <hip/hip_bf16.h>

typedef __attribute__((ext_vector_type(8))) __bf16 bf16x8;
typedef __attribute__((ext_vector_type(4))) float f32x4;
typedef __hip_bfloat16 bf16;

#define SCALE_Q 0.17677669529663687f

#define LDSP(p) ((__attribute__((address_space(3))) unsigned int*)(unsigned long long)(p))
#define GPTR(p) ((const __attribute__((address_space(1))) unsigned int*)(unsigned long long)(p))
#define GLD16(gp, lp) __builtin_amdgcn_global_load_lds(GPTR(gp), LDSP(lp), 16, 0, 0)

// exact-grade GELU: Abramowitz-Stegun 7.1.26 erf (|err| < 1.5e-7)
__device__ inline float gelu_f(float x) {
  const float ax = fabsf(x) * 0.70710678118654752f;
  const float t = __builtin_amdgcn_rcpf(__builtin_fmaf(0.3275911f, ax, 1.0f));
  const float poly = t * __builtin_fmaf(t, __builtin_fmaf(t, __builtin_fmaf(t,
                     __builtin_fmaf(t, 1.061405429f, -1.453152027f),
                     1.421413741f), -0.284496736f), 0.254829592f);
  const float er = __builtin_fmaf(-poly, __expf(-ax * ax), 1.0f);
  return 0.5f * x * (1.0f + copysignf(er, x));
}

// ---------------- weight fp32 -> bf16 (row-major, for LDS-staged gemm_bt) ----------------
__global__ void cvt_kernel(const float* __restrict__ in, bf16* __restrict__ out, int n) {
  int i = blockIdx.x * 256 + threadIdx.x;
  if (i < n) out[i] = __float2bfloat16(in[i]);
}

// ---- weight fp32 -> bf16 in MFMA B-fragment order ----
// src [N][K] row-major; dst chunk (n>>4, k>>5) holds [lg=(k>>3)&3][lr=n&15][e=k&7].
template<int K, int KC>
__global__ void cvt_frag_kernel(const float* __restrict__ in, bf16* __restrict__ out, int total) {
  int i = blockIdx.x * 256 + threadIdx.x;
  if (i < total) {
    const int n = i / K, k = i - n * K;
    out[((n >> 4) * KC + (k >> 5)) * 512 + ((k >> 3) & 3) * 128 + (n & 15) * 8 + (k & 7)] =
        __float2bfloat16(in[i]);
  }
}

// ------- fused LN1 + shifted-window gather + QKV GEMM (BM=64, fragment-B from L2) -------
// Phase 1: each wave LN-normalizes 8 rows of x (ln_kernel math/order, gather indexing)
// into swizzled Ab (bytes == old zw staging). Phase 2: fc1-style barrier-free kc loop,
// waves = 2 row-groups x 4 col-groups (144 cols, 9 c16 chunks); EPI0 scatter (R1 code).
__global__ __launch_bounds__(512, 2) void qkv_ln1(const float* __restrict__ x,
                                                  const float* __restrict__ n1w,
                                                  const float* __restrict__ n1b,
                                                  const bf16* __restrict__ qwt,
                                                  const float* __restrict__ qb,
                                                  bf16* __restrict__ outp) {
  __shared__ __align__(16) char Ab[24576];  // 3 groups x [64 rows][8 slots][16B]
  const int tid = threadIdx.x;
  const long m0 = (long)blockIdx.x * 64;
  const int lane = tid & 63, wid = tid >> 6;
  const int lg = lane >> 4, lr = lane & 15;

  // ---- LN1 + gather: each wave 8 rows ----
  #pragma unroll
  for (int t8 = 0; t8 < 8; t8++) {
    const int row = wid * 8 + t8;
    const long t = m0 + row;
    const int b_ = (int)(t >> 6), n = (int)(t & 63);
    const int b = b_ >> 10, wk = b_ & 1023, wi = wk >> 5, wj = wk & 31;
    const int hf = (wi * 8 + (n >> 3) + 4) & 255, wf = (wj * 8 + (n & 7) + 4) & 255;
    const long g = (((long)b * 256 + hf) * 256 + wf) * 192;
    const float x0 = x[g + lane], x1 = x[g + 64 + lane], x2 = x[g + 128 + lane];
    float s = x0 + x1 + x2;
    float s2 = x0 * x0 + x1 * x1 + x2 * x2;
    #pragma unroll
    for (int msk = 1; msk < 64; msk <<= 1) { s += __shfl_xor(s, msk); s2 += __shfl_xor(s2, msk); }
    const float mu = s * (1.0f / 192.0f);
    const float rstd = rsqrtf(s2 * (1.0f / 192.0f) - mu * mu + 1e-5f);
    #pragma unroll
    for (int p = 0; p < 3; p++) {
      const int ch = p * 64 + lane;
      const float xv = (p == 0) ? x0 : (p == 1) ? x1 : x2;
      const float v = (xv - mu) * rstd * n1w[ch] + n1b[ch];
      const int c = (ch >> 3) & 7;
      const int slot = c ^ (row & 7);
      *(unsigned short*)(Ab + p * 8192 + row * 128 + slot * 16 + (ch & 7) * 2) =
          __builtin_bit_cast(unsigned short, __float2bfloat16(v));
    }
  }
  __syncthreads();

  // ---- QKV GEMM: barrier-free kc loop, B fragments direct from L2 ----
  const int wrr = (wid >> 2) * 32;
  const int wcg = wid & 3;           // col-group: 144 cols = 9 c16 chunks
  f32x4 acc[2][9];
  #pragma unroll
  for (int i = 0; i < 2; i++)
    #pragma unroll
    for (int j = 0; j < 9; j++) acc[i][j] = (f32x4){0.f, 0.f, 0.f, 0.f};

  const int c16base = wcg * 9;
  #pragma unroll
  for (int kc = 0; kc < 6; kc++) {
    const int q = kc >> 1;
    const int kk = (kc & 1) * 4 + lg;
    bf16x8 af[2], bfr[9];
    #pragma unroll
    for (int i = 0; i < 2; i++) {
      const int row = wrr + i * 16 + lr;
      af[i] = *(const bf16x8*)(Ab + q * 8192 + row * 128 + ((kk ^ (row & 7)) * 16));
    }
    #pragma unroll
    for (int j = 0; j < 9; j++)
      bfr[j] = *(const bf16x8*)(qwt + ((c16base + j) * 6 + kc) * 512 + lane * 8);
    #pragma unroll
    for (int i = 0; i < 2; i++)
      #pragma unroll
      for (int j = 0; j < 9; j++)
        acc[i][j] = __builtin_amdgcn_mfma_f32_16x16x32_bf16(af[i], bfr[j], acc[i][j], 0, 0, 0);
  }

  // ---- EPI0 scatter (+q scale) — per-element, R1-proven code ----
  #pragma unroll
  for (int i = 0; i < 2; i++) {
    #pragma unroll
    for (int j = 0; j < 9; j++) {
      #pragma unroll
      for (int r = 0; r < 4; r++) {
        const long m = m0 + wrr + i * 16 + lg * 4 + r;
        const int cn = wcg * 144 + j * 16 + lr;
        float v = acc[i][j][r] + qb[cn];
        const long b_ = m >> 6; const int n = (int)(m & 63);
        const int which = cn / 192, rem = cn - which * 192, head = rem >> 5, d = rem & 31;
        if (which == 0) v *= SCALE_Q;
        outp[((b_ * 6 + head) * 3 + which) * 2048 + n * 32 + d] = __float2bfloat16(v);
      }
    }
  }
}

// ---------------- GEMM (R15-proven): BM=128 BN=192 BK=64, 512 threads ----------------
// EPI 1: proj + window-reverse+roll + residual -> h_buf f32
template<int EPI>
__global__ __launch_bounds__(512, 4) void gemm_bt(const bf16* __restrict__ A,
                                                  const bf16* __restrict__ Bw,
                                                  const float* __restrict__ bias,
                                                  int K, void* __restrict__ outp,
                                                  const float* __restrict__ aux1,
                                                  const float* __restrict__ aux2) {
  __shared__ __align__(16) bf16 Ald[128 * 64];
  __shared__ __align__(16) bf16 Bld[192 * 64];
  const int tid = threadIdx.x;
  const int n0 = blockIdx.x * 192;
  const long m0 = (long)blockIdx.y * 128;
  const int lane = tid & 63, wid = tid >> 6;
  const int wr = (wid >> 1) * 32, wc = (wid & 1) * 96;
  const int lg = lane >> 4, lr = lane & 15;
  const int l3 = lane >> 3, l7 = lane & 7;
  const int chunk = l7 ^ l3;

  const bf16* aptr = A + (m0 + wid * 16 + l3) * (long)K + chunk * 8;
  const bf16* bptr = Bw + (n0 + wid * 24 + l3) * (long)K + chunk * 8;
  char* alds = (char*)Ald + wid * 16 * 128;
  char* blds = (char*)Bld + wid * 24 * 128;
  const long rk8 = 8 * (long)K;

  f32x4 acc[2][6];
  #pragma unroll
  for (int i = 0; i < 2; i++)
    #pragma unroll
    for (int j = 0; j < 6; j++) acc[i][j] = (f32x4){0.f, 0.f, 0.f, 0.f};

  for (int k0 = 0; k0 < K; k0 += 64) {
    GLD16(aptr + k0, alds);
    GLD16(aptr + rk8 + k0, alds + 1024);
    GLD16(bptr + k0, blds);
    GLD16(bptr + rk8 + k0, blds + 1024);
    GLD16(bptr + 2 * rk8 + k0, blds + 2048);
    __syncthreads();
    #pragma unroll
    for (int ks = 0; ks < 2; ks++) {
      bf16x8 af[2], bfr[6];
      #pragma unroll
      for (int i = 0; i < 2; i++) {
        const int row = wr + i * 16 + lr;
        af[i] = *(const bf16x8*)((const char*)Ald + row * 128 + (((ks * 4 + lg) ^ (row & 7)) * 16));
      }
      #pragma unroll
      for (int j = 0; j < 6; j++) {
        const int row = wc + j * 16 + lr;
        bfr[j] = *(const bf16x8*)((const char*)Bld + row * 128 + (((ks * 4 + lg) ^ (row & 7)) * 16));
      }
      #pragma unroll
      for (int i = 0; i < 2; i++)
        #pragma unroll
        for (int j = 0; j < 6; j++)
          acc[i][j] = __builtin_amdgcn_mfma_f32_16x16x32_bf16(af[i], bfr[j], acc[i][j], 0, 0, 0);
    }
    __syncthreads();
  }

  #pragma unroll
  for (int i = 0; i < 2; i++) {
    #pragma unroll
    for (int j = 0; j < 6; j++) {
      #pragma unroll
      for (int r = 0; r < 4; r++) {
        const long m = m0 + wr + i * 16 + lg * 4 + r;
        const int cn = n0 + wc + j * 16 + lr;
        float v = acc[i][j][r] + bias[cn];
        if (EPI == 0) {
          const long b_ = m >> 6; const int n = (int)(m & 63);
          const int which = cn / 192, rem = cn - which * 192, head = rem >> 5, d = rem & 31;
          if (which == 0) v *= SCALE_Q;
          ((bf16*)outp)[((b_ * 6 + head) * 3 + which) * 2048 + n * 32 + d] = __float2bfloat16(v);
        } else {
          const long b_ = m >> 6; const int n = (int)(m & 63);
          const int b = (int)(b_ >> 10), wk = (int)(b_ & 1023), wi = wk >> 5, wj = wk & 31;
          const int i_ = n >> 3, j_ = n & 7;
          const int hf = (wi * 8 + i_ + 4) & 255, wf = (wj * 8 + j_ + 4) & 255;
          const long g = (((long)b * 256 + hf) * 256 + wf) * 192 + cn;
          ((float*)outp)[g] = aux1[g] + v;
        }
      }
    }
  }
}

// ------------ fused MLP v6 (best: 409us): out = h + fc2(gelu(fc1(LN2(h)))) — BM=64 ------------
__global__ __launch_bounds__(512, 2) void mlp_fused(const float* __restrict__ hbuf,
                                                    const float* __restrict__ n2w,
                                                    const float* __restrict__ n2b,
                                                    const bf16* __restrict__ w1t,
                                                    const float* __restrict__ b1,
                                                    const bf16* __restrict__ w2t,
                                                    const float* __restrict__ b2,
                                                    float* __restrict__ outp) {
  __shared__ __align__(16) char smem[122880];
  char* Ab = smem;          // h_ln tile: 3 groups x [64 rows][8 slots][16B] = 24576
  char* G  = smem + 24576;  // g tile: [64 rows][96 slots][16B] = 98304

  const int tid = threadIdx.x;
  const long m0 = (long)blockIdx.x * 64;
  const int lane = tid & 63, wid = tid >> 6;
  const int lg = lane >> 4, lr = lane & 15;

  #pragma unroll
  for (int t8 = 0; t8 < 8; t8++) {
    const int row = wid * 8 + t8;
    const long g = (m0 + row) * 192;
    const float x0 = hbuf[g + lane], x1 = hbuf[g + 64 + lane], x2 = hbuf[g + 128 + lane];
    float s = x0 + x1 + x2;
    float s2 = x0 * x0 + x1 * x1 + x2 * x2;
    #pragma unroll
    for (int msk = 1; msk < 64; msk <<= 1) { s += __shfl_xor(s, msk); s2 += __shfl_xor(s2, msk); }
    const float mu = s * (1.0f / 192.0f);
    const float rstd = rsqrtf(s2 * (1.0f / 192.0f) - mu * mu + 1e-5f);
    #pragma unroll
    for (int p = 0; p < 3; p++) {
      const int ch = p * 64 + lane;
      const float xv = (p == 0) ? x0 : (p == 1) ? x1 : x2;
      const float v = (xv - mu) * rstd * n2w[ch] + n2b[ch];
      const int c = (ch >> 3) & 7;
      const int slot = c ^ (row & 7);
      *(unsigned short*)(Ab + p * 8192 + row * 128 + slot * 16 + (ch & 7) * 2) =
          __builtin_bit_cast(unsigned short, __float2bfloat16(v));
    }
  }
  __syncthreads();

  f32x4 acc1[4][6];
  #pragma unroll
  for (int i = 0; i < 4; i++)
    #pragma unroll
    for (int j = 0; j < 6; j++) acc1[i][j] = (f32x4){0.f, 0.f, 0.f, 0.f};

  const int c16base = wid * 6;
  #pragma unroll
  for (int kc = 0; kc < 6; kc++) {
    const int q = kc >> 1;
    const int kk = (kc & 1) * 4 + lg;
    bf16x8 af[4], bfr[6];
    #pragma unroll
    for (int i = 0; i < 4; i++) {
      const int row = i * 16 + lr;
      af[i] = *(const bf16x8*)(Ab + q * 8192 + row * 128 + ((kk ^ (row & 7)) * 16));
    }
    #pragma unroll
    for (int j = 0; j < 6; j++)
      bfr[j] = *(const bf16x8*)(w1t + ((c16base + j) * 6 + kc) * 512 + lane * 8);
    #pragma unroll
    for (int i = 0; i < 4; i++)
      #pragma unroll
      for (int j = 0; j < 6; j++)
        acc1[i][j] = __builtin_amdgcn_mfma_f32_16x16x32_bf16(af[i], bfr[j], acc1[i][j], 0, 0, 0);
  }

  #pragma unroll
  for (int j = 0; j < 6; j++) {
    const int n = wid * 96 + j * 16 + lr;
    const float bj = b1[n];
    const int c = n >> 3;
    #pragma unroll
    for (int i = 0; i < 4; i++) {
      #pragma unroll
      for (int r = 0; r < 4; r++) {
        const int m = i * 16 + lg * 4 + r;
        const int slot = (c & ~7) | ((c & 7) ^ (m & 7));
        *(unsigned short*)(G + m * 1536 + slot * 16 + (n & 7) * 2) =
            __builtin_bit_cast(unsigned short, __float2bfloat16(gelu_f(acc1[i][j][r] + bj)));
      }
    }
  }
  __syncthreads();

  const int wt = wid >> 2, wn = wid & 3;
  f32x4 acc2[2][3];
  #pragma unroll
  for (int i = 0; i < 2; i++)
    #pragma unroll
    for (int j = 0; j < 3; j++) acc2[i][j] = (f32x4){0.f, 0.f, 0.f, 0.f};

  for (int kt = 0; kt < 24; kt++) {
    const int c2 = kt * 4 + lg;
    bf16x8 af2[2], bfr2[3];
    #pragma unroll
    for (int i = 0; i < 2; i++) {
      const int grow = wt * 32 + i * 16 + lr;
      const int slot2 = (c2 & ~7) | ((c2 & 7) ^ (grow & 7));
      af2[i] = *(const bf16x8*)(G + grow * 1536 + slot2 * 16);
    }
    #pragma unroll
    for (int j = 0; j < 3; j++)
      bfr2[j] = *(const bf16x8*)(w2t + ((wn * 3 + j) * 24 + kt) * 512 + lane * 8);
    #pragma unroll
    for (int i = 0; i < 2; i++)
      #pragma unroll
      for (int j = 0; j < 3; j++)
        acc2[i][j] = __builtin_amdgcn_mfma_f32_16x16x32_bf16(af2[i], bfr2[j], acc2[i][j], 0, 0, 0);
  }

  #pragma unroll
  for (int j = 0; j < 3; j++) {
    const int cn = wn * 48 + j * 16 + lr;
    const float bj = b2[cn];
    #pragma unroll
    for (int i = 0; i < 2; i++) {
      #pragma unroll
      for (int r = 0; r < 4; r++) {
        const long m = m0 + wt * 32 + i * 16 + lg * 4 + r;
        outp[m * 192 + cn] = acc2[i][j][r] + bj + hbuf[m * 192 + cn];
      }
    }
  }
}

// ---------------- windowed attention: one wave per (window, head) — proven round-1 ----------------
__global__ __launch_bounds__(64) void attn_kernel(const bf16* __restrict__ qkv,
                                                  const float* __restrict__ rpb,
                                                  bf16* __restrict__ outp) {
  __shared__ __align__(16) char smem[14848];
  __shared__ float rps[225];
  const int bid = blockIdx.x;
  const int b_ = bid / 6, head = bid - b_ * 6;
  const int lane = threadIdx.x;
  const long base = ((long)b_ * 6 + head) * 3 * 2048;

  for (int t = lane; t < 225; t += 64) rps[t] = rpb[t * 6 + head];

  #pragma unroll
  for (int q = 0; q < 4; q++) {
    const int f = q * 64 + lane, row = f >> 2, c = f & 3;
    *(uint4*)(smem + row * 80 + c * 16) = *(const uint4*)(qkv + base + row * 32 + c * 8);
    *(uint4*)(smem + 5120 + row * 80 + c * 16) = *(const uint4*)(qkv + base + 2048 + row * 32 + c * 8);
  }
  {
    const bf16* vsrc = qkv + base + 4096 + lane * 32;
    bf16 vv[32];
    #pragma unroll
    for (int q = 0; q < 4; q++) *(uint4*)&vv[q * 8] = *(const uint4*)(vsrc + q * 8);
    bf16* vt = (bf16*)(smem + 10240);
    #pragma unroll
    for (int d = 0; d < 32; d++) vt[d * 72 + lane] = vv[d];
  }
  __syncthreads();

  const int lg = lane >> 4, lr = lane & 15;
  const f32x4 z4 = {0.f, 0.f, 0.f, 0.f};
  f32x4 s[4][4];
  {
    bf16x8 a[4], b[4];
    #pragma unroll
    for (int fi = 0; fi < 4; fi++)
      a[fi] = *(const bf16x8*)(smem + (fi * 16 + lr) * 80 + lg * 16);
    #pragma unroll
    for (int fj = 0; fj < 4; fj++)
      b[fj] = *(const bf16x8*)(smem + 5120 + (fj * 16 + lr) * 80 + lg * 16);
    #pragma unroll
    for (int fi = 0; fi < 4; fi++)
      #pragma unroll
      for (int fj = 0; fj < 4; fj++)
        s[fi][fj] = __builtin_amdgcn_mfma_f32_16x16x32_bf16(a[fi], b[fj], z4, 0, 0, 0);
  }

  const int wk = b_ & 1023; const int wi = wk >> 5, wj = wk & 31;
  const bool eh = (wi == 31), ew = (wj == 31);
  bf16* P = (bf16*)smem;
  #pragma unroll
  for (int fi = 0; fi < 4; fi++) {
    #pragma unroll
    for (int r = 0; r < 4; r++) {
      const int n = fi * 16 + lg * 4 + r;
      const int i1 = n >> 3, j1 = n & 7;
      const int labn = (eh ? (i1 < 4 ? 3 : 6) : 0) + (ew ? (j1 < 4 ? 1 : 2) : 0);
      float vals[4];
      #pragma unroll
      for (int fj = 0; fj < 4; fj++) {
        const int m = fj * 16 + lr;
        const int i2 = m >> 3, j2 = m & 7;
        const int labm = (eh ? (i2 < 4 ? 3 : 6) : 0) + (ew ? (j2 < 4 ? 1 : 2) : 0);
        vals[fj] = s[fi][fj][r] + rps[(i1 - i2 + 7) * 15 + (j1 - j2 + 7)]
                 + (labn != labm ? -100.0f : 0.0f);
      }
      float mx = fmaxf(fmaxf(vals[0], vals[1]), fmaxf(vals[2], vals[3]));
      #pragma unroll
      for (int msk = 1; msk < 16; msk <<= 1) mx = fmaxf(mx, __shfl_xor(mx, msk));
      float pe[4]; float sum = 0.f;
      #pragma unroll
      for (int fj = 0; fj < 4; fj++) { pe[fj] = __expf(vals[fj] - mx); sum += pe[fj]; }
      #pragma unroll
      for (int msk = 1; msk < 16; msk <<= 1) sum += __shfl_xor(sum, msk);
      const float rinv = 1.0f / sum;
      #pragma unroll
      for (int fj = 0; fj < 4; fj++)
        P[n * 72 + fj * 16 + lr] = __float2bfloat16(pe[fj] * rinv);
    }
  }
  __syncthreads();

  f32x4 o[4][2];
  #pragma unroll
  for (int fi = 0; fi < 4; fi++)
    #pragma unroll
    for (int fd = 0; fd < 2; fd++) o[fi][fd] = z4;
  const bf16* vt = (const bf16*)(smem + 10240);
  #pragma unroll
  for (int ks = 0; ks < 2; ks++) {
    bf16x8 pa[4], vb[2];
    #pragma unroll
    for (int fi = 0; fi < 4; fi++)
      pa[fi] = *(const bf16x8*)(P + (fi * 16 + lr) * 72 + ks * 32 + lg * 8);
    #pragma unroll
    for (int fd = 0; fd < 2; fd++)
      vb[fd] = *(const bf16x8*)(vt + (fd * 16 + lr) * 72 + ks * 32 + lg * 8);
    #pragma unroll
    for (int fi = 0; fi < 4; fi++)
      #pragma unroll
      for (int fd = 0; fd < 2; fd++)
        o[fi][fd] = __builtin_amdgcn_mfma_f32_16x16x32_bf16(pa[fi], vb[fd], o[fi][fd], 0, 0, 0);
  }
  #pragma unroll
  for (int fi = 0; fi < 4; fi++)
    #pragma unroll
    for (int fd = 0; fd < 2; fd++)
      #pragma unroll
      for (int r = 0; r < 4; r++) {
        const int n = fi * 16 + lg * 4 + r;
        outp[((long)b_ * 64 + n) * 192 + head * 32 + fd * 16 + lr] = __float2bfloat16(o[fi][fd][r]);
      }
}

extern "C" void kernel_launch(void* const* d_in, const int* in_sizes, int n_in,
                              void* d_out, int out_size, void* d_ws, size_t ws_size,
                              hipStream_t stream) {
  const float* x      = (const float*)d_in[0];
  const float* qkv_w  = (const float*)d_in[1];
  const float* qkv_b  = (const float*)d_in[2];
  const float* proj_w = (const float*)d_in[3];
  const float* proj_b = (const float*)d_in[4];
  const float* rpb    = (const float*)d_in[5];
  const float* n1_w   = (const float*)d_in[6];
  const float* n1_b   = (const float*)d_in[7];
  const float* n2_w   = (const float*)d_in[8];
  const float* n2_b   = (const float*)d_in[9];
  const float* fc1_w  = (const float*)d_in[10];
  const float* fc1_b  = (const float*)d_in[11];
  const float* fc2_w  = (const float*)d_in[12];
  const float* fc2_b  = (const float*)d_in[13];

  char* ws = (char*)d_ws;
  // workspace: qkv_w frags [0,221184) | proj_w row-major [221184,294912)
  //            fc1_w frags [294912,589824) | fc2_w frags [589824,884736)
  // r1 attn_out [1MiB,+100.7MB) | r2 qkv [101711872,+302MB) | hbuf [504365056,+201MB)
  bf16* qkvw_t  = (bf16*)(ws);
  bf16* projw_h = (bf16*)(ws + 221184);
  bf16* fc1w_t  = (bf16*)(ws + 294912);
  bf16* fc2w_t  = (bf16*)(ws + 589824);
  bf16* r1      = (bf16*)(ws + (1L << 20));
  bf16* r2      = (bf16*)(ws + 101711872L);
  float* hbuf   = (float*)(ws + 504365056L);

  cvt_frag_kernel<192, 6><<<432, 256, 0, stream>>>(qkv_w, qkvw_t, 110592);
  cvt_kernel<<<144, 256, 0, stream>>>(proj_w, projw_h, 36864);
  cvt_frag_kernel<192, 6><<<576, 256, 0, stream>>>(fc1_w, fc1w_t, 147456);
  cvt_frag_kernel<768, 24><<<576, 256, 0, stream>>>(fc2_w, fc2w_t, 147456);

  // fused LN1 + gather + QKV -> per-(window,head) Q|K|V blocks (r2)
  qkv_ln1<<<4096, 512, 0, stream>>>(x, n1_w, n1_b, qkvw_t, qkv_b, r2);
  // windowed attention -> attn_out (r1)
  attn_kernel<<<24576, 64, 0, stream>>>(r2, rpb, r1);
  // proj + window-reverse + roll + residual -> h_buf
  gemm_bt<1><<<dim3(1, 2048), 512, 0, stream>>>(r1, projw_h, proj_b, 192, hbuf, x, nullptr);
  // fused LN2 + MLP: out = h + fc2(gelu(fc1(LN2(h))))
  mlp_fused<<<4096, 512, 0, stream>>>(hbuf, n2_w, n2_b, fc1w_t, fc1_b, fc2w_t, fc2_b,
                                      (float*)d_out);
}

// Round 19
// 802.084 us; speedup vs baseline: 1.0343x; 1.0021x over previous
//
#include <hip/hip_runtime.h>
#include <hip/hip_bf16.h>

typedef __attribute__((ext_vector_type(8))) __bf16 bf16x8;
typedef __attribute__((ext_vector_type(4))) float f32x4;
typedef __hip_bfloat16 bf16;

#define SCALE_Q 0.17677669529663687f

// exact-grade GELU: Abramowitz-Stegun 7.1.26 erf (|err| < 1.5e-7)
__device__ inline float gelu_f(float x) {
  const float ax = fabsf(x) * 0.70710678118654752f;
  const float t = __builtin_amdgcn_rcpf(__builtin_fmaf(0.3275911f, ax, 1.0f));
  const float poly = t * __builtin_fmaf(t, __builtin_fmaf(t, __builtin_fmaf(t,
                     __builtin_fmaf(t, 1.061405429f, -1.453152027f),
                     1.421413741f), -0.284496736f), 0.254829592f);
  const float er = __builtin_fmaf(-poly, __expf(-ax * ax), 1.0f);
  return 0.5f * x * (1.0f + copysignf(er, x));
}

// ---- weight fp32 -> bf16 in MFMA B-fragment order ----
// src [N][K] row-major; dst chunk (n>>4, k>>5) holds [lg=(k>>3)&3][lr=n&15][e=k&7].
template<int K, int KC>
__global__ void cvt_frag_kernel(const float* __restrict__ in, bf16* __restrict__ out, int total) {
  int i = blockIdx.x * 256 + threadIdx.x;
  if (i < total) {
    const int n = i / K, k = i - n * K;
    out[((n >> 4) * KC + (k >> 5)) * 512 + ((k >> 3) & 3) * 128 + (n & 15) * 8 + (k & 7)] =
        __float2bfloat16(in[i]);
  }
}

// ===== window mega-kernel: LN1+gather + QKV + attention + proj + residual -> hbuf =====
// One block per window (64 tokens), 512 threads (8 waves). All phase code is the
// byte-proven R18/R1 code; only data routing moved from global to LDS.
__global__ __launch_bounds__(512, 2) void win_attn(const float* __restrict__ x,
                                                   const float* __restrict__ n1w,
                                                   const float* __restrict__ n1b,
                                                   const bf16* __restrict__ qwt,
                                                   const float* __restrict__ qb,
                                                   const float* __restrict__ rpb,
                                                   const bf16* __restrict__ pwt,
                                                   const float* __restrict__ pb,
                                                   float* __restrict__ hbuf) {
  __shared__ __align__(16) char smem[119072];
  char* Qt = smem;                        // 6 heads x 5120 = 30720  (P overlays Q+K later)
  char* Kt = smem + 30720;                // 30720
  char* Vtb = smem + 61440;               // 6 x 4608 = 27648
  char* Ab = smem + 89088;                // 24576: LN1 tile, later O tile (dead after QKV)
  float* rpl = (float*)(smem + 113664);   // 6 x 225 floats = 5400

  const int tid = threadIdx.x;
  const int blk = blockIdx.x;             // window index b_
  const long m0 = (long)blk * 64;
  const int lane = tid & 63, wid = tid >> 6;
  const int lg = lane >> 4, lr = lane & 15;

  // stage per-head rpb tables: rpl[head][t] = rpb[t*6+head]
  for (int t = tid; t < 1350; t += 512) {
    const int hh = t / 225, tt = t - hh * 225;
    rpl[hh * 225 + tt] = rpb[tt * 6 + hh];
  }

  // ---- Phase 1: LN1 + shifted-window gather -> Ab (R18 code verbatim) ----
  #pragma unroll
  for (int t8 = 0; t8 < 8; t8++) {
    const int row = wid * 8 + t8;
    const long t = m0 + row;
    const int b_ = (int)(t >> 6), n = (int)(t & 63);
    const int b = b_ >> 10, wk = b_ & 1023, wi = wk >> 5, wj = wk & 31;
    const int hf = (wi * 8 + (n >> 3) + 4) & 255, wf = (wj * 8 + (n & 7) + 4) & 255;
    const long g = (((long)b * 256 + hf) * 256 + wf) * 192;
    const float x0 = x[g + lane], x1 = x[g + 64 + lane], x2 = x[g + 128 + lane];
    float s = x0 + x1 + x2;
    float s2 = x0 * x0 + x1 * x1 + x2 * x2;
    #pragma unroll
    for (int msk = 1; msk < 64; msk <<= 1) { s += __shfl_xor(s, msk); s2 += __shfl_xor(s2, msk); }
    const float mu = s * (1.0f / 192.0f);
    const float rstd = rsqrtf(s2 * (1.0f / 192.0f) - mu * mu + 1e-5f);
    #pragma unroll
    for (int p = 0; p < 3; p++) {
      const int ch = p * 64 + lane;
      const float xv = (p == 0) ? x0 : (p == 1) ? x1 : x2;
      const float v = (xv - mu) * rstd * n1w[ch] + n1b[ch];
      const int c = (ch >> 3) & 7;
      const int slot = c ^ (row & 7);
      *(unsigned short*)(Ab + p * 8192 + row * 128 + slot * 16 + (ch & 7) * 2) =
          __builtin_bit_cast(unsigned short, __float2bfloat16(v));
    }
  }
  __syncthreads();  // B1: Ab + rpl ready

  // ---- Phase 2: QKV GEMM (R18 kc loop verbatim), epilogue -> LDS Q/K/Vt ----
  {
    const int wrr = (wid >> 2) * 32;
    const int wcg = wid & 3;
    f32x4 acc[2][9];
    #pragma unroll
    for (int i = 0; i < 2; i++)
      #pragma unroll
      for (int j = 0; j < 9; j++) acc[i][j] = (f32x4){0.f, 0.f, 0.f, 0.f};
    const int c16base = wcg * 9;
    #pragma unroll
    for (int kc = 0; kc < 6; kc++) {
      const int q = kc >> 1;
      const int kk = (kc & 1) * 4 + lg;
      bf16x8 af[2], bfr[9];
      #pragma unroll
      for (int i = 0; i < 2; i++) {
        const int row = wrr + i * 16 + lr;
        af[i] = *(const bf16x8*)(Ab + q * 8192 + row * 128 + ((kk ^ (row & 7)) * 16));
      }
      #pragma unroll
      for (int j = 0; j < 9; j++)
        bfr[j] = *(const bf16x8*)(qwt + ((c16base + j) * 6 + kc) * 512 + lane * 8);
      #pragma unroll
      for (int i = 0; i < 2; i++)
        #pragma unroll
        for (int j = 0; j < 9; j++)
          acc[i][j] = __builtin_amdgcn_mfma_f32_16x16x32_bf16(af[i], bfr[j], acc[i][j], 0, 0, 0);
    }
    __syncthreads();  // B2a: all Ab reads done before O-tile later; harmless extra
    #pragma unroll
    for (int i = 0; i < 2; i++) {
      #pragma unroll
      for (int j = 0; j < 9; j++) {
        #pragma unroll
        for (int r = 0; r < 4; r++) {
          const int n = wrr + i * 16 + lg * 4 + r;        // token row in window
          const int cn = wcg * 144 + j * 16 + lr;
          float v = acc[i][j][r] + qb[cn];
          const int which = cn / 192, rem = cn - which * 192, head = rem >> 5, d = rem & 31;
          unsigned short us;
          if (which == 0) { v *= SCALE_Q; us = __builtin_bit_cast(unsigned short, __float2bfloat16(v));
            *(unsigned short*)(Qt + head * 5120 + n * 80 + d * 2) = us; }
          else if (which == 1) { us = __builtin_bit_cast(unsigned short, __float2bfloat16(v));
            *(unsigned short*)(Kt + head * 5120 + n * 80 + d * 2) = us; }
          else { us = __builtin_bit_cast(unsigned short, __float2bfloat16(v));
            *(unsigned short*)(Vtb + head * 4608 + (d * 72 + n) * 2) = us; }
        }
      }
    }
  }
  __syncthreads();  // B2: Q/K/Vt ready

  // ---- Phase 3: attention (R1 code verbatim; head = wid for wid<6) ----
  const f32x4 z4 = {0.f, 0.f, 0.f, 0.f};
  f32x4 s[4][4];
  const int head = wid;
  if (wid < 6) {
    bf16x8 a[4], b[4];
    #pragma unroll
    for (int fi = 0; fi < 4; fi++)
      a[fi] = *(const bf16x8*)(Qt + head * 5120 + (fi * 16 + lr) * 80 + lg * 16);
    #pragma unroll
    for (int fj = 0; fj < 4; fj++)
      b[fj] = *(const bf16x8*)(Kt + head * 5120 + (fj * 16 + lr) * 80 + lg * 16);
    #pragma unroll
    for (int fi = 0; fi < 4; fi++)
      #pragma unroll
      for (int fj = 0; fj < 4; fj++)
        s[fi][fj] = __builtin_amdgcn_mfma_f32_16x16x32_bf16(a[fi], b[fj], z4, 0, 0, 0);
  }
  __syncthreads();  // B3: all Q/K reads done before P overlays them

  bf16* P = (bf16*)(smem + head * 9216);  // overlays Q+K region (6*9216 = 55296 <= 61440)
  if (wid < 6) {
    const int wk = blk & 1023; const int wi = wk >> 5, wj = wk & 31;
    const bool eh = (wi == 31), ew = (wj == 31);
    const float* rps = rpl + head * 225;
    #pragma unroll
    for (int fi = 0; fi < 4; fi++) {
      #pragma unroll
      for (int r = 0; r < 4; r++) {
        const int n = fi * 16 + lg * 4 + r;
        const int i1 = n >> 3, j1 = n & 7;
        const int labn = (eh ? (i1 < 4 ? 3 : 6) : 0) + (ew ? (j1 < 4 ? 1 : 2) : 0);
        float vals[4];
        #pragma unroll
        for (int fj = 0; fj < 4; fj++) {
          const int m = fj * 16 + lr;
          const int i2 = m >> 3, j2 = m & 7;
          const int labm = (eh ? (i2 < 4 ? 3 : 6) : 0) + (ew ? (j2 < 4 ? 1 : 2) : 0);
          vals[fj] = s[fi][fj][r] + rps[(i1 - i2 + 7) * 15 + (j1 - j2 + 7)]
                   + (labn != labm ? -100.0f : 0.0f);
        }
        float mx = fmaxf(fmaxf(vals[0], vals[1]), fmaxf(vals[2], vals[3]));
        #pragma unroll
        for (int msk = 1; msk < 16; msk <<= 1) mx = fmaxf(mx, __shfl_xor(mx, msk));
        float pe[4]; float sum = 0.f;
        #pragma unroll
        for (int fj = 0; fj < 4; fj++) { pe[fj] = __expf(vals[fj] - mx); sum += pe[fj]; }
        #pragma unroll
        for (int msk = 1; msk < 16; msk <<= 1) sum += __shfl_xor(sum, msk);
        const float rinv = 1.0f / sum;
        #pragma unroll
        for (int fj = 0; fj < 4; fj++)
          P[n * 72 + fj * 16 + lr] = __float2bfloat16(pe[fj] * rinv);
      }
    }
  }
  __syncthreads();  // B4

  if (wid < 6) {
    f32x4 o[4][2];
    #pragma unroll
    for (int fi = 0; fi < 4; fi++)
      #pragma unroll
      for (int fd = 0; fd < 2; fd++) o[fi][fd] = z4;
    const bf16* vt = (const bf16*)(Vtb + head * 4608);
    #pragma unroll
    for (int ks = 0; ks < 2; ks++) {
      bf16x8 pa[4], vb[2];
      #pragma unroll
      for (int fi = 0; fi < 4; fi++)
        pa[fi] = *(const bf16x8*)(P + (fi * 16 + lr) * 72 + ks * 32 + lg * 8);
      #pragma unroll
      for (int fd = 0; fd < 2; fd++)
        vb[fd] = *(const bf16x8*)(vt + (fd * 16 + lr) * 72 + ks * 32 + lg * 8);
      #pragma unroll
      for (int fi = 0; fi < 4; fi++)
        #pragma unroll
        for (int fd = 0; fd < 2; fd++)
          o[fi][fd] = __builtin_amdgcn_mfma_f32_16x16x32_bf16(pa[fi], vb[fd], o[fi][fd], 0, 0, 0);
    }
    // O -> Ab-format tile (proven mlp G-write pattern): row n, col ch = head*32+fd*16+lr
    #pragma unroll
    for (int fi = 0; fi < 4; fi++)
      #pragma unroll
      for (int fd = 0; fd < 2; fd++)
        #pragma unroll
        for (int r = 0; r < 4; r++) {
          const int n = fi * 16 + lg * 4 + r;
          const int ch = head * 32 + fd * 16 + lr;
          const int p = ch >> 6, c = (ch >> 3) & 7;
          const int slot = c ^ (n & 7);
          *(unsigned short*)(Ab + p * 8192 + n * 128 + slot * 16 + (ch & 7) * 2) =
              __builtin_bit_cast(unsigned short, __float2bfloat16(o[fi][fd][r]));
        }
  }
  __syncthreads();  // B5: O tile ready

  // ---- Phase 4: proj (fc1-pattern kc loop) + gather residual -> hbuf (EPI1 verbatim) ----
  {
    const int wrr2 = (wid >> 2) * 32, wcg2 = wid & 3;
    f32x4 accp[2][3];
    #pragma unroll
    for (int i = 0; i < 2; i++)
      #pragma unroll
      for (int j = 0; j < 3; j++) accp[i][j] = (f32x4){0.f, 0.f, 0.f, 0.f};
    #pragma unroll
    for (int kc = 0; kc < 6; kc++) {
      const int q = kc >> 1;
      const int kk = (kc & 1) * 4 + lg;
      bf16x8 af[2], bfr[3];
      #pragma unroll
      for (int i = 0; i < 2; i++) {
        const int row = wrr2 + i * 16 + lr;
        af[i] = *(const bf16x8*)(Ab + q * 8192 + row * 128 + ((kk ^ (row & 7)) * 16));
      }
      #pragma unroll
      for (int j = 0; j < 3; j++)
        bfr[j] = *(const bf16x8*)(pwt + ((wcg2 * 3 + j) * 6 + kc) * 512 + lane * 8);
      #pragma unroll
      for (int i = 0; i < 2; i++)
        #pragma unroll
        for (int j = 0; j < 3; j++)
          accp[i][j] = __builtin_amdgcn_mfma_f32_16x16x32_bf16(af[i], bfr[j], accp[i][j], 0, 0, 0);
    }
    #pragma unroll
    for (int i = 0; i < 2; i++) {
      #pragma unroll
      for (int j = 0; j < 3; j++) {
        #pragma unroll
        for (int r = 0; r < 4; r++) {
          const long m = m0 + wrr2 + i * 16 + lg * 4 + r;
          const int cn = wcg2 * 48 + j * 16 + lr;
          const float v = accp[i][j][r] + pb[cn];
          const long b_ = m >> 6; const int n = (int)(m & 63);
          const int b = (int)(b_ >> 10), wk = (int)(b_ & 1023), wi = wk >> 5, wj = wk & 31;
          const int i_ = n >> 3, j_ = n & 7;
          const int hf = (wi * 8 + i_ + 4) & 255, wf = (wj * 8 + j_ + 4) & 255;
          const long g = (((long)b * 256 + hf) * 256 + wf) * 192 + cn;
          hbuf[g] = x[g] + v;   // h = shortcut + proj(attn)
        }
      }
    }
  }
}

// ------------ fused MLP v6 (best: 409us): out = h + fc2(gelu(fc1(LN2(h)))) — BM=64 ------------
__global__ __launch_bounds__(512, 2) void mlp_fused(const float* __restrict__ hbuf,
                                                    const float* __restrict__ n2w,
                                                    const float* __restrict__ n2b,
                                                    const bf16* __restrict__ w1t,
                                                    const float* __restrict__ b1,
                                                    const bf16* __restrict__ w2t,
                                                    const float* __restrict__ b2,
                                                    float* __restrict__ outp) {
  __shared__ __align__(16) char smem[122880];
  char* Ab = smem;          // h_ln tile: 3 groups x [64 rows][8 slots][16B] = 24576
  char* G  = smem + 24576;  // g tile: [64 rows][96 slots][16B] = 98304

  const int tid = threadIdx.x;
  const long m0 = (long)blockIdx.x * 64;
  const int lane = tid & 63, wid = tid >> 6;
  const int lg = lane >> 4, lr = lane & 15;

  #pragma unroll
  for (int t8 = 0; t8 < 8; t8++) {
    const int row = wid * 8 + t8;
    const long g = (m0 + row) * 192;
    const float x0 = hbuf[g + lane], x1 = hbuf[g + 64 + lane], x2 = hbuf[g + 128 + lane];
    float s = x0 + x1 + x2;
    float s2 = x0 * x0 + x1 * x1 + x2 * x2;
    #pragma unroll
    for (int msk = 1; msk < 64; msk <<= 1) { s += __shfl_xor(s, msk); s2 += __shfl_xor(s2, msk); }
    const float mu = s * (1.0f / 192.0f);
    const float rstd = rsqrtf(s2 * (1.0f / 192.0f) - mu * mu + 1e-5f);
    #pragma unroll
    for (int p = 0; p < 3; p++) {
      const int ch = p * 64 + lane;
      const float xv = (p == 0) ? x0 : (p == 1) ? x1 : x2;
      const float v = (xv - mu) * rstd * n2w[ch] + n2b[ch];
      const int c = (ch >> 3) & 7;
      const int slot = c ^ (row & 7);
      *(unsigned short*)(Ab + p * 8192 + row * 128 + slot * 16 + (ch & 7) * 2) =
          __builtin_bit_cast(unsigned short, __float2bfloat16(v));
    }
  }
  __syncthreads();

  f32x4 acc1[4][6];
  #pragma unroll
  for (int i = 0; i < 4; i++)
    #pragma unroll
    for (int j = 0; j < 6; j++) acc1[i][j] = (f32x4){0.f, 0.f, 0.f, 0.f};

  const int c16base = wid * 6;
  #pragma unroll
  for (int kc = 0; kc < 6; kc++) {
    const int q = kc >> 1;
    const int kk = (kc & 1) * 4 + lg;
    bf16x8 af[4], bfr[6];
    #pragma unroll
    for (int i = 0; i < 4; i++) {
      const int row = i * 16 + lr;
      af[i] = *(const bf16x8*)(Ab + q * 8192 + row * 128 + ((kk ^ (row & 7)) * 16));
    }
    #pragma unroll
    for (int j = 0; j < 6; j++)
      bfr[j] = *(const bf16x8*)(w1t + ((c16base + j) * 6 + kc) * 512 + lane * 8);
    #pragma unroll
    for (int i = 0; i < 4; i++)
      #pragma unroll
      for (int j = 0; j < 6; j++)
        acc1[i][j] = __builtin_amdgcn_mfma_f32_16x16x32_bf16(af[i], bfr[j], acc1[i][j], 0, 0, 0);
  }

  #pragma unroll
  for (int j = 0; j < 6; j++) {
    const int n = wid * 96 + j * 16 + lr;
    const float bj = b1[n];
    const int c = n >> 3;
    #pragma unroll
    for (int i = 0; i < 4; i++) {
      #pragma unroll
      for (int r = 0; r < 4; r++) {
        const int m = i * 16 + lg * 4 + r;
        const int slot = (c & ~7) | ((c & 7) ^ (m & 7));
        *(unsigned short*)(G + m * 1536 + slot * 16 + (n & 7) * 2) =
            __builtin_bit_cast(unsigned short, __float2bfloat16(gelu_f(acc1[i][j][r] + bj)));
      }
    }
  }
  __syncthreads();

  const int wt = wid >> 2, wn = wid & 3;
  f32x4 acc2[2][3];
  #pragma unroll
  for (int i = 0; i < 2; i++)
    #pragma unroll
    for (int j = 0; j < 3; j++) acc2[i][j] = (f32x4){0.f, 0.f, 0.f, 0.f};

  for (int kt = 0; kt < 24; kt++) {
    const int c2 = kt * 4 + lg;
    bf16x8 af2[2], bfr2[3];
    #pragma unroll
    for (int i = 0; i < 2; i++) {
      const int grow = wt * 32 + i * 16 + lr;
      const int slot2 = (c2 & ~7) | ((c2 & 7) ^ (grow & 7));
      af2[i] = *(const bf16x8*)(G + grow * 1536 + slot2 * 16);
    }
    #pragma unroll
    for (int j = 0; j < 3; j++)
      bfr2[j] = *(const bf16x8*)(w2t + ((wn * 3 + j) * 24 + kt) * 512 + lane * 8);
    #pragma unroll
    for (int i = 0; i < 2; i++)
      #pragma unroll
      for (int j = 0; j < 3; j++)
        acc2[i][j] = __builtin_amdgcn_mfma_f32_16x16x32_bf16(af2[i], bfr2[j], acc2[i][j], 0, 0, 0);
  }

  #pragma unroll
  for (int j = 0; j < 3; j++) {
    const int cn = wn * 48 + j * 16 + lr;
    const float bj = b2[cn];
    #pragma unroll
    for (int i = 0; i < 2; i++) {
      #pragma unroll
      for (int r = 0; r < 4; r++) {
        const long m = m0 + wt * 32 + i * 16 + lg * 4 + r;
        outp[m * 192 + cn] = acc2[i][j][r] + bj + hbuf[m * 192 + cn];
      }
    }
  }
}

extern "C" void kernel_launch(void* const* d_in, const int* in_sizes, int n_in,
                              void* d_out, int out_size, void* d_ws, size_t ws_size,
                              hipStream_t stream) {
  const float* x      = (const float*)d_in[0];
  const float* qkv_w  = (const float*)d_in[1];
  const float* qkv_b  = (const float*)d_in[2];
  const float* proj_w = (const float*)d_in[3];
  const float* proj_b = (const float*)d_in[4];
  const float* rpb    = (const float*)d_in[5];
  const float* n1_w   = (const float*)d_in[6];
  const float* n1_b   = (const float*)d_in[7];
  const float* n2_w   = (const float*)d_in[8];
  const float* n2_b   = (const float*)d_in[9];
  const float* fc1_w  = (const float*)d_in[10];
  const float* fc1_b  = (const float*)d_in[11];
  const float* fc2_w  = (const float*)d_in[12];
  const float* fc2_b  = (const float*)d_in[13];

  char* ws = (char*)d_ws;
  // workspace: all weights fragment-order [0, 884736); hbuf at 1 MiB (+201.3 MB).
  bf16* qkvw_t  = (bf16*)(ws);
  bf16* projw_t = (bf16*)(ws + 221184);
  bf16* fc1w_t  = (bf16*)(ws + 294912);
  bf16* fc2w_t  = (bf16*)(ws + 589824);
  float* hbuf   = (float*)(ws + (1L << 20));

  cvt_frag_kernel<192, 6><<<432, 256, 0, stream>>>(qkv_w, qkvw_t, 110592);
  cvt_frag_kernel<192, 6><<<144, 256, 0, stream>>>(proj_w, projw_t, 36864);
  cvt_frag_kernel<192, 6><<<576, 256, 0, stream>>>(fc1_w, fc1w_t, 147456);
  cvt_frag_kernel<768, 24><<<576, 256, 0, stream>>>(fc2_w, fc2w_t, 147456);

  // fused LN1 + QKV + attention + proj + residual -> hbuf (one block per window)
  win_attn<<<4096, 512, 0, stream>>>(x, n1_w, n1_b, qkvw_t, qkv_b, rpb, projw_t, proj_b, hbuf);
  // fused LN2 + MLP: out = h + fc2(gelu(fc1(LN2(h))))
  mlp_fused<<<4096, 512, 0, stream>>>(hbuf, n2_w, n2_b, fc1w_t, fc1_b, fc2w_t, fc2_b,
                                      (float*)d_out);
}